// Round 2
// baseline (857.691 us; speedup 1.0000x reference)
//
#include <hip/hip_runtime.h>
#include <math.h>
#include <stdint.h>

// KWinners: per-row top-K binary mask with duty-cycle boosting.
// x: (4096, 16384) fp32, duty: (16384,) fp32, out: (4096, 16384) fp32 0/1 mask.
//
// Round-4 design:
//  - khi (top 16 bits of order-preserving key) in 16 VGPRs/thread (uint2 kh[8],
//    statically indexed). No 32 KB LDS array.
//  - Probe counting via plain per-lane compare+add (NO ballot: convergent ops
//    blocked load pipelining in round-3; this is the round-2 scheme that
//    overlapped loads well) + wave shuffle reduce.
//  - NEW: second-level probe refinement ON THE CANDIDATES' full 32-bit keys
//    (interpolated thresholds, counted over mm<=2048 LDS entries). Shrinks the
//    exact-rank set from m~400 to <=64, killing the O(m^2) rank pass that
//    dominated rounds 2-3 (~50-95 us/kernel).
//  - Exact for ANY input: khi refinement loop (m > CAP), generic in-bracket
//    rank fallback (|S| > 128), serial radix fallback (mm > CAP).

#define N_UNITS 16384
#define K_WIN 655
#define NT 512
#define NPROBE 11
#define CAP 2048
#define SCAP 128
#define ITERS (N_UNITS / (NT * 4))  // 8

// Order-preserving float -> uint map: larger float => larger key.
__device__ __forceinline__ uint32_t fkey(float f) {
    uint32_t b = __float_as_uint(f);
    uint32_t m = (uint32_t)((int32_t)b >> 31) | 0x80000000u;
    return b ^ m;
}

__global__ void boost_kernel(const float* __restrict__ duty,
                             float* __restrict__ bf, int n) {
    int i = blockIdx.x * blockDim.x + threadIdx.x;
    if (i < n) {
        const float td = 0.03997802734375f;  // 655/16384, exact in fp32
        float s = td - duty[i];              // fp32 subtract, matches ref
        bf[i] = (float)exp((double)s);       // correctly-rounded fp32 exp
    }
}

__global__ __launch_bounds__(NT, 8) void kwinners_kernel(
    const float* __restrict__ x, const float* __restrict__ bf,
    float* __restrict__ out) {
    __shared__ uint32_t red[(NT / 64) * NPROBE];  // per-wave partial counts
    __shared__ int cglob[NPROBE];
    __shared__ uint32_t cand_idx[CAP];  // 8 KB
    __shared__ uint32_t cand_key[CAP];  // 8 KB
    __shared__ uint32_t s_idx[SCAP];
    __shared__ uint32_t s_key[SCAP];
    __shared__ int sc[2];  // 0: candidate count, 1: sub-bracket count

    const int tid = threadIdx.x;
    const int lane = tid & 63;
    const int w = tid >> 6;
    const int row = blockIdx.x;
    const float4* xrow = (const float4*)(x + (size_t)row * N_UNITS);
    const float4* bfv = (const float4*)bf;
    float* orow = out + (size_t)row * N_UNITS;

    if (tid == 0) { sc[0] = 0; sc[1] = 0; }  // ordered by reduce barrier

    // Probes tuned for N(0,1)*boost; fkey(literal) constant-folds.
    int P[NPROBE];
    {
        const float pv[NPROBE] = {1.90f, 1.70f, 1.55f, 1.43f, 1.33f, 1.25f,
                                  1.18f, 1.12f, 1.06f, 0.99f, 0.90f};
#pragma unroll
        for (int p = 0; p < NPROBE; ++p) P[p] = (int)(fkey(pv[p]) >> 16);
    }

    int cnt[NPROBE];
#pragma unroll
    for (int p = 0; p < NPROBE; ++p) cnt[p] = 0;

    uint2 kh[ITERS];  // khi for this thread's 32 elements (16 VGPRs)

    // ---- fused: global load -> keys -> khi in regs + per-lane counting ----
#pragma unroll
    for (int j = 0; j < ITERS; ++j) {
        int i4 = tid + j * NT;
        float4 xv = xrow[i4];
        float4 bv = bfv[i4];
        int h0 = (int)(fkey(xv.x * bv.x) >> 16);
        int h1 = (int)(fkey(xv.y * bv.y) >> 16);
        int h2 = (int)(fkey(xv.z * bv.z) >> 16);
        int h3 = (int)(fkey(xv.w * bv.w) >> 16);
        kh[j].x = (uint32_t)h0 | ((uint32_t)h1 << 16);
        kh[j].y = (uint32_t)h2 | ((uint32_t)h3 << 16);
#pragma unroll
        for (int p = 0; p < NPROBE; ++p)
            cnt[p] += (h0 > P[p]) + (h1 > P[p]) + (h2 > P[p]) + (h3 > P[p]);
    }

    // ---- block reduction of per-lane counters -> cglob ----
    auto reduce_counts = [&]() {
#pragma unroll
        for (int p = 0; p < NPROBE; ++p) {
            int v = cnt[p];
#pragma unroll
            for (int m2 = 32; m2 >= 1; m2 >>= 1) v += __shfl_xor(v, m2, 64);
            if (lane == 0) red[w * NPROBE + p] = (uint32_t)v;
        }
        __syncthreads();
        if (tid < NPROBE) {
            int s = 0;
#pragma unroll
            for (int ww = 0; ww < NT / 64; ++ww) s += (int)red[ww * NPROBE + tid];
            cglob[tid] = s;
        }
        __syncthreads();
    };
    reduce_counts();

    // ---- bracket (lo, hi]: count(>hi) < K <= count(>lo) ----
    int lo, hi, cab, cgl;  // cab = count(>hi), cgl = count(>lo)
    {
        int j = 0;
        while (j < NPROBE && cglob[j] < K_WIN) ++j;
        if (j == 0) {
            lo = P[0]; cgl = cglob[0]; hi = 65535; cab = 0;
        } else if (j == NPROBE) {
            lo = -1; cgl = N_UNITS; hi = P[NPROBE - 1]; cab = cglob[NPROBE - 1];
        } else {
            lo = P[j]; cgl = cglob[j]; hi = P[j - 1]; cab = cglob[j - 1];
        }
    }
    int m = cgl - cab;

    // ---- khi refinement (exact, terminates; ~never runs on benchmark) ----
    while (m > CAP && (hi - lo) > 1) {
#pragma unroll
        for (int p = 0; p < NPROBE; ++p)
            P[p] = lo + (int)(((long)(hi - lo) * (NPROBE - p)) / (NPROBE + 1));
#pragma unroll
        for (int p = 0; p < NPROBE; ++p) cnt[p] = 0;
#pragma unroll
        for (int j = 0; j < ITERS; ++j) {
            int h0 = (int)(kh[j].x & 0xFFFFu), h1 = (int)(kh[j].x >> 16);
            int h2 = (int)(kh[j].y & 0xFFFFu), h3 = (int)(kh[j].y >> 16);
#pragma unroll
            for (int p = 0; p < NPROBE; ++p)
                cnt[p] += (h0 > P[p]) + (h1 > P[p]) + (h2 > P[p]) + (h3 > P[p]);
        }
        reduce_counts();
        int j = 0;
        while (j < NPROBE && cglob[j] < K_WIN) ++j;
        if (j == 0) {
            lo = P[0]; cgl = cglob[0];  // hi, cab unchanged
        } else if (j == NPROBE) {
            hi = P[NPROBE - 1]; cab = cglob[NPROBE - 1];  // lo, cgl unchanged
        } else {
            lo = P[j]; cgl = cglob[j]; hi = P[j - 1]; cab = cglob[j - 1];
        }
        m = cgl - cab;
    }

    // ---- fused bulk mask write (coalesced float4) + candidate gather ----
#pragma unroll
    for (int j = 0; j < ITERS; ++j) {
        int f = tid + j * NT;
        int h0 = (int)(kh[j].x & 0xFFFFu), h1 = (int)(kh[j].x >> 16);
        int h2 = (int)(kh[j].y & 0xFFFFu), h3 = (int)(kh[j].y >> 16);
        float4 o;
        o.x = (h0 > hi) ? 1.0f : 0.0f;
        o.y = (h1 > hi) ? 1.0f : 0.0f;
        o.z = (h2 > hi) ? 1.0f : 0.0f;
        o.w = (h3 > hi) ? 1.0f : 0.0f;
        ((float4*)orow)[f] = o;
        int base = f * 4;
        int h[4] = {h0, h1, h2, h3};
#pragma unroll
        for (int e = 0; e < 4; ++e) {
            if (h[e] > lo && h[e] <= hi) {
                int p = atomicAdd(&sc[0], 1);
                if (p < CAP) cand_idx[p] = (uint32_t)(base + e);
            }
        }
    }
    __syncthreads();
    const int mm = sc[0];
    const int need = K_WIN - cab;

    // ---- fetch full keys for candidates (scattered, L2/L3-hit) ----
    const float* xr = x + (size_t)row * N_UNITS;
    const int mc = (mm <= CAP) ? mm : 0;
    for (int j = tid; j < mc; j += NT) {
        int i = (int)cand_idx[j];
        cand_key[j] = fkey(xr[i] * bf[i]);
    }
    __syncthreads();  // orders cand_key writes AND bulk global writes

    if (mm <= CAP) {
        // ---- refinement on candidate full keys: shrink set to <=64 ----
        // invariant: count(key > gLo) = cGL >= need, count(key > gHi) = cHi < need
        long gLo = -1, gHi = 0xFFFFFFFFL;
        int cHi = 0, cGL = mm;
        int inB = mm, guard = 0;
        while (inB > 64 && (gHi - gLo) > 1 && ++guard <= 40) {
            long T[NPROBE];
            unsigned long range = (unsigned long)(gHi - gLo);
#pragma unroll
            for (int p = 0; p < NPROBE; ++p)
                T[p] = gLo + (long)(range * (unsigned long)(NPROBE - p) /
                                    (NPROBE + 1));
#pragma unroll
            for (int p = 0; p < NPROBE; ++p) cnt[p] = 0;
            for (int j = tid; j < mm; j += NT) {
                long k = (long)cand_key[j];
#pragma unroll
                for (int p = 0; p < NPROBE; ++p) cnt[p] += (k > T[p]);
            }
            reduce_counts();
            int j = 0;
            while (j < NPROBE && cglob[j] < need) ++j;
            if (j == 0) {
                gLo = T[0]; cGL = cglob[0];
            } else if (j == NPROBE) {
                gHi = T[NPROBE - 1]; cHi = cglob[NPROBE - 1];
            } else {
                gLo = T[j]; cGL = cglob[j]; gHi = T[j - 1]; cHi = cglob[j - 1];
            }
            inB = cGL - cHi;
        }
        const int need2 = need - cHi;  // >= 1 by invariant

        // ---- write key>gHi winners; compact sub-bracket S into s_* ----
        for (int j = tid; j < mm; j += NT) {
            long k = (long)cand_key[j];
            if (k > gHi) {
                orow[cand_idx[j]] = 1.0f;
            } else if (k > gLo) {
                int p = atomicAdd(&sc[1], 1);
                if (p < SCAP) { s_key[p] = cand_key[j]; s_idx[p] = cand_idx[j]; }
            }
        }
        __syncthreads();
        const int sS = sc[1];  // == inB

        if (sS <= SCAP) {
            // exact rank among <=128 entries; (key desc, idx asc) = jax top_k
            for (int j = tid; j < sS; j += NT) {
                uint32_t myk = s_key[j];
                uint32_t myi = s_idx[j];
                int r = 0;
                for (int l = 0; l < sS; ++l) {
                    uint32_t lk = s_key[l];
                    r += (lk > myk) || (lk == myk && s_idx[l] < myi);
                }
                if (r < need2) orow[myi] = 1.0f;
            }
        } else {
            // rare (heavy ties / guard exit): rank in-bracket against full list
            for (int j = tid; j < mm; j += NT) {
                long k = (long)cand_key[j];
                if (k > gLo && k <= gHi) {
                    uint32_t myk = cand_key[j];
                    uint32_t myi = cand_idx[j];
                    int r = 0;
                    for (int l = 0; l < mm; ++l) {
                        long lk2 = (long)cand_key[l];
                        if (lk2 > gLo && lk2 <= gHi) {
                            uint32_t lk = cand_key[l];
                            r += (lk > myk) || (lk == myk && cand_idx[l] < myi);
                        }
                    }
                    if (r < need2) orow[myi] = 1.0f;
                }
            }
        }
    } else if (tid == 0) {
        // Fallback (unreachable on benchmark data): > CAP ties at khi == hi.
        // Serial radix on low 16 bits of the full key; exact, index-ordered.
        uint32_t* h8 = cand_idx;  // reuse as 256-entry histogram
        for (int b = 0; b < 256; ++b) h8[b] = 0;
        for (int i = 0; i < N_UNITS; ++i) {
            uint32_t kf = fkey(xr[i] * bf[i]);
            if ((int)(kf >> 16) == hi) h8[(kf & 0xFFFFu) >> 8]++;
        }
        int acc = 0, d1 = 0, need2 = 0;
        for (int b = 255; b >= 0; --b) {
            int c = (int)h8[b];
            if (acc + c >= need) { d1 = b; need2 = need - acc; break; }
            acc += c;
        }
        for (int b = 0; b < 256; ++b) h8[b] = 0;
        for (int i = 0; i < N_UNITS; ++i) {
            uint32_t kf = fkey(xr[i] * bf[i]);
            if ((int)(kf >> 16) == hi && (int)((kf & 0xFFFFu) >> 8) == d1)
                h8[kf & 0xFFu]++;
        }
        int acc2 = 0, d2 = 0, need3 = 0;
        for (int b = 255; b >= 0; --b) {
            int c = (int)h8[b];
            if (acc2 + c >= need2) { d2 = b; need3 = need2 - acc2; break; }
            acc2 += c;
        }
        uint32_t Tlo = ((uint32_t)d1 << 8) | (uint32_t)d2;
        int r = 0;
        for (int i = 0; i < N_UNITS; ++i) {
            uint32_t kf = fkey(xr[i] * bf[i]);
            if ((int)(kf >> 16) == hi) {
                uint32_t kl = kf & 0xFFFFu;
                if (kl > Tlo) orow[i] = 1.0f;
                else if (kl == Tlo && r < need3) { orow[i] = 1.0f; ++r; }
            }
        }
    }
}

extern "C" void kernel_launch(void* const* d_in, const int* in_sizes, int n_in,
                              void* d_out, int out_size, void* d_ws,
                              size_t ws_size, hipStream_t stream) {
    const float* x = (const float*)d_in[0];
    const float* duty = (const float*)d_in[1];
    float* out = (float*)d_out;
    float* bf = (float*)d_ws;  // 16384 floats = 64 KB scratch

    hipLaunchKernelGGL(boost_kernel, dim3(N_UNITS / 256), dim3(256), 0, stream,
                       duty, bf, N_UNITS);
    int rows = out_size / N_UNITS;  // 4096
    hipLaunchKernelGGL(kwinners_kernel, dim3(rows), dim3(NT), 0, stream, x, bf,
                       out);
}

// Round 3
// 650.275 us; speedup vs baseline: 1.3190x; 1.3190x over previous
//
#include <hip/hip_runtime.h>
#include <math.h>
#include <stdint.h>

// KWinners: per-row top-K binary mask with duty-cycle boosting.
// x: (4096, 16384) fp32, duty: (16384,) fp32, out: (4096, 16384) fp32 0/1 mask.
//
// Round-5 design (zero scattered global accesses):
//  - Full 32-bit order-preserving keys for this thread's 32 elements held in
//    32 VGPRs (uint4 kk[8], statically indexed).
//  - Probe counting per-lane compare+add vs uniform full-key constants.
//  - Bracket refinement in FULL-KEY space from registers (interpolated
//    thresholds, >=12x range shrink per round, <=2 rounds typical, provably
//    terminates at range<=1). No candidate spill arrays, no global re-reads.
//  - Winners in-bracket resolved by exact rank over <=128 compacted entries
//    (key desc, idx asc = jax.lax.top_k), marked in a 2 KB LDS bitmap.
//  - Single coalesced float4 output pass: (key > hi) | bitmap. NO scattered
//    global writes (round-4's 4.7x write amplification came from these).
//  - Pathological >128-way exact-key ties at the boundary: serial index-order
//    patch by thread 0 (unreachable on benchmark data, exact for any input).

#define N_UNITS 16384
#define K_WIN 655
#define NT 512
#define NPROBE 11
#define SCAP 128
#define ITERS (N_UNITS / (NT * 4))  // 8

// Order-preserving float -> uint map: larger float => larger key.
__device__ __forceinline__ uint32_t fkey(float f) {
    uint32_t b = __float_as_uint(f);
    uint32_t m = (uint32_t)((int32_t)b >> 31) | 0x80000000u;
    return b ^ m;
}

__global__ void boost_kernel(const float* __restrict__ duty,
                             float* __restrict__ bf, int n) {
    int i = blockIdx.x * blockDim.x + threadIdx.x;
    if (i < n) {
        const float td = 0.03997802734375f;  // 655/16384, exact in fp32
        float s = td - duty[i];              // fp32 subtract, matches ref
        bf[i] = (float)exp((double)s);       // correctly-rounded fp32 exp
    }
}

__global__ __launch_bounds__(NT, 6) void kwinners_kernel(
    const float* __restrict__ x, const float* __restrict__ bf,
    float* __restrict__ out) {
    __shared__ uint32_t red[(NT / 64) * NPROBE];  // per-wave partial counts
    __shared__ int cglob[NPROBE];
    __shared__ uint32_t s_key[SCAP];
    __shared__ uint32_t s_idx[SCAP];
    __shared__ uint32_t bmap[N_UNITS / 32];  // 2 KB winner bitmap
    __shared__ int sc[1];

    const int tid = threadIdx.x;
    const int lane = tid & 63;
    const int w = tid >> 6;
    const int row = blockIdx.x;
    const float4* xrow = (const float4*)(x + (size_t)row * N_UNITS);
    const float4* bfv = (const float4*)bf;
    float* orow = out + (size_t)row * N_UNITS;

    bmap[tid] = 0u;           // NT == N_UNITS/32 exactly
    if (tid == 0) sc[0] = 0;  // ordered before first use by reduce barriers

    // Probes tuned for N(0,1)*boost, as full-key thresholds:
    // count(khi > P) == count(key > (fkey(pv) | 0xFFFF)). Constant-folded.
    uint32_t PF[NPROBE];
    {
        const float pv[NPROBE] = {1.90f, 1.70f, 1.55f, 1.43f, 1.33f, 1.25f,
                                  1.18f, 1.12f, 1.06f, 0.99f, 0.90f};
#pragma unroll
        for (int p = 0; p < NPROBE; ++p) PF[p] = fkey(pv[p]) | 0xFFFFu;
    }

    int cnt[NPROBE];
#pragma unroll
    for (int p = 0; p < NPROBE; ++p) cnt[p] = 0;

    uint4 kk[ITERS];  // full keys for this thread's 32 elements (32 VGPRs)

    // ---- fused: global load -> full keys in regs + per-lane counting ----
    // (pure loads + VALU: no LDS ops, atomics, or convergent ops, so the 16
    //  dwordx4 loads pipeline ahead of the compare chains)
#pragma unroll
    for (int j = 0; j < ITERS; ++j) {
        int i4 = tid + j * NT;
        float4 xv = xrow[i4];
        float4 bv = bfv[i4];
        kk[j].x = fkey(xv.x * bv.x);
        kk[j].y = fkey(xv.y * bv.y);
        kk[j].z = fkey(xv.z * bv.z);
        kk[j].w = fkey(xv.w * bv.w);
#pragma unroll
        for (int p = 0; p < NPROBE; ++p)
            cnt[p] += (kk[j].x > PF[p]) + (kk[j].y > PF[p]) +
                      (kk[j].z > PF[p]) + (kk[j].w > PF[p]);
    }

    // ---- block reduction of per-lane counters -> cglob ----
    auto reduce_counts = [&]() {
#pragma unroll
        for (int p = 0; p < NPROBE; ++p) {
            int v = cnt[p];
#pragma unroll
            for (int m2 = 32; m2 >= 1; m2 >>= 1) v += __shfl_xor(v, m2, 64);
            if (lane == 0) red[w * NPROBE + p] = (uint32_t)v;
        }
        __syncthreads();
        if (tid < NPROBE) {
            int s = 0;
#pragma unroll
            for (int ww = 0; ww < NT / 64; ++ww) s += (int)red[ww * NPROBE + tid];
            cglob[tid] = s;
        }
        __syncthreads();
    };
    reduce_counts();

    // ---- bracket (lo, hi] in full-key space: count(>hi) < K <= count(>lo) ----
    long lo, hi;   // thresholds in [-1, 2^32-1]
    int cab, cgl;  // cab = count(>hi), cgl = count(>lo)
    {
        int j = 0;
        while (j < NPROBE && cglob[j] < K_WIN) ++j;
        if (j == 0) {
            lo = (long)PF[0]; cgl = cglob[0]; hi = 0xFFFFFFFFL; cab = 0;
        } else if (j == NPROBE) {
            lo = -1; cgl = N_UNITS; hi = (long)PF[NPROBE - 1];
            cab = cglob[NPROBE - 1];
        } else {
            lo = (long)PF[j]; cgl = cglob[j]; hi = (long)PF[j - 1];
            cab = cglob[j - 1];
        }
    }
    int inB = cgl - cab;

    // ---- full-key refinement from registers until <= SCAP in bracket ----
    // Range shrinks >= 12x per round -> terminates (range<=1 => pure ties).
    // Block-uniform condition: barriers inside are safe.
    while (inB > SCAP && (hi - lo) > 1) {
        unsigned long range = (unsigned long)(hi - lo);
        // p-outer so only one 64-bit threshold is live at a time (VGPR).
#pragma unroll
        for (int p = 0; p < NPROBE; ++p) {
            long Tp = lo + (long)(range * (unsigned long)(NPROBE - p) /
                                  (NPROBE + 1));
            int c = 0;
#pragma unroll
            for (int j = 0; j < ITERS; ++j)
                c += ((long)kk[j].x > Tp) + ((long)kk[j].y > Tp) +
                     ((long)kk[j].z > Tp) + ((long)kk[j].w > Tp);
            cnt[p] = c;
        }
        reduce_counts();
        int j = 0;
        while (j < NPROBE && cglob[j] < K_WIN) ++j;
        const long llo = lo;  // recompute thresholds from OLD bracket
        auto Tof = [&](int p) {
            return llo + (long)(range * (unsigned long)(NPROBE - p) /
                                (NPROBE + 1));
        };
        if (j == 0) {
            lo = Tof(0); cgl = cglob[0];  // hi, cab unchanged
        } else if (j == NPROBE) {
            hi = Tof(NPROBE - 1); cab = cglob[NPROBE - 1];  // lo unchanged
        } else {
            lo = Tof(j); cgl = cglob[j]; hi = Tof(j - 1); cab = cglob[j - 1];
        }
        inB = cgl - cab;
    }
    const int need = K_WIN - cab;  // >= 1 by bracket invariant

    if (inB <= SCAP) {
        // ---- compact in-bracket (key, idx) into LDS ----
#pragma unroll
        for (int j = 0; j < ITERS; ++j) {
            int base = (tid + j * NT) * 4;
            uint32_t kv[4] = {kk[j].x, kk[j].y, kk[j].z, kk[j].w};
#pragma unroll
            for (int e = 0; e < 4; ++e) {
                long k = (long)kv[e];
                if (k > lo && k <= hi) {
                    int p = atomicAdd(&sc[0], 1);
                    if (p < SCAP) {
                        s_key[p] = kv[e];
                        s_idx[p] = (uint32_t)(base + e);
                    }
                }
            }
        }
        __syncthreads();
        const int sS = sc[0];  // == inB (exact same comparisons as counts)

        // ---- exact rank among <=128; (key desc, idx asc) = jax top_k ----
        for (int jj = tid; jj < sS; jj += NT) {
            uint32_t myk = s_key[jj];
            uint32_t myi = s_idx[jj];
            int r = 0;
            for (int l = 0; l < sS; ++l) {
                uint32_t lk = s_key[l];
                r += (lk > myk) || (lk == myk && s_idx[l] < myi);
            }
            if (r < need) atomicOr(&bmap[myi >> 5], 1u << (myi & 31));
        }
    } else {
        // Pathological: range collapsed (hi-lo==1) with >SCAP exact-key ties
        // at the boundary. Winners among key==hi are the first `need` by
        // index. Serial, unreachable on benchmark data; exact for any input.
        if (tid == 0) {
            const float* xr = x + (size_t)row * N_UNITS;
            int r = 0;
            for (int i = 0; i < N_UNITS && r < need; ++i) {
                uint32_t kf = fkey(xr[i] * bf[i]);
                if ((long)kf == hi) {
                    bmap[i >> 5] |= (1u << (i & 31));
                    ++r;
                }
            }
        }
    }
    __syncthreads();

    // ---- single coalesced output pass: (key > hi) | bitmap ----
#pragma unroll
    for (int j = 0; j < ITERS; ++j) {
        int f = tid + j * NT;
        uint32_t bm = bmap[f >> 3];  // word holds bits for 8 float4 groups
        int sh = (f & 7) * 4;
        float4 o;
        o.x = (((long)kk[j].x > hi) || ((bm >> (sh + 0)) & 1u)) ? 1.0f : 0.0f;
        o.y = (((long)kk[j].y > hi) || ((bm >> (sh + 1)) & 1u)) ? 1.0f : 0.0f;
        o.z = (((long)kk[j].z > hi) || ((bm >> (sh + 2)) & 1u)) ? 1.0f : 0.0f;
        o.w = (((long)kk[j].w > hi) || ((bm >> (sh + 3)) & 1u)) ? 1.0f : 0.0f;
        ((float4*)orow)[f] = o;
    }
}

extern "C" void kernel_launch(void* const* d_in, const int* in_sizes, int n_in,
                              void* d_out, int out_size, void* d_ws,
                              size_t ws_size, hipStream_t stream) {
    const float* x = (const float*)d_in[0];
    const float* duty = (const float*)d_in[1];
    float* out = (float*)d_out;
    float* bf = (float*)d_ws;  // 16384 floats = 64 KB scratch

    hipLaunchKernelGGL(boost_kernel, dim3(N_UNITS / 256), dim3(256), 0, stream,
                       duty, bf, N_UNITS);
    int rows = out_size / N_UNITS;  // 4096
    hipLaunchKernelGGL(kwinners_kernel, dim3(rows), dim3(NT), 0, stream, x, bf,
                       out);
}

// Round 4
// 516.443 us; speedup vs baseline: 1.6608x; 1.2591x over previous
//
#include <hip/hip_runtime.h>
#include <math.h>
#include <stdint.h>

// KWinners: per-row top-K binary mask with duty-cycle boosting.
// x: (4096, 16384) fp32, duty: (16384,) fp32, out: (4096, 16384) fp32 0/1 mask.
//
// Round-6 design (round-5 structure, spill fixed):
//  - Full 32-bit order-preserving keys for this thread's 32 elements held in
//    32 VGPRs (uint4 kk[8], statically indexed).
//  - __launch_bounds__(NT, 1): round-5's (NT, 6) made the allocator clamp to
//    40 VGPRs and spill kk to scratch (-> +300 MB of scratch writebacks,
//    WRITE_SIZE 572 MB vs 268 MB output). One wave/EU minimum lets the
//    ~72-100 VGPRs this kernel needs stay resident; 4 waves/SIMD is ample
//    occupancy for a streaming kernel (in-flight-bytes needed ~9 KB/CU).
//  - Probe counting per-lane compare+add vs uniform full-key constants.
//  - Bracket refinement in FULL-KEY space from registers; SCAP=256 so the
//    common bracket population (200-500) usually needs <=1 extra round.
//  - Winners in-bracket resolved by exact rank over <=256 compacted entries
//    (key desc, idx asc = jax.lax.top_k), marked in a 2 KB LDS bitmap.
//  - Single coalesced float4 output pass: (key > hi) | bitmap. No scattered
//    global writes, no RMW amplification.
//  - Pathological >256-way exact-key ties at the boundary: serial index-order
//    patch by thread 0 (unreachable on benchmark data, exact for any input).

#define N_UNITS 16384
#define K_WIN 655
#define NT 512
#define NPROBE 11
#define SCAP 256
#define ITERS (N_UNITS / (NT * 4))  // 8

// Order-preserving float -> uint map: larger float => larger key.
__device__ __forceinline__ uint32_t fkey(float f) {
    uint32_t b = __float_as_uint(f);
    uint32_t m = (uint32_t)((int32_t)b >> 31) | 0x80000000u;
    return b ^ m;
}

__global__ void boost_kernel(const float* __restrict__ duty,
                             float* __restrict__ bf, int n) {
    int i = blockIdx.x * blockDim.x + threadIdx.x;
    if (i < n) {
        const float td = 0.03997802734375f;  // 655/16384, exact in fp32
        float s = td - duty[i];              // fp32 subtract, matches ref
        bf[i] = (float)exp((double)s);       // correctly-rounded fp32 exp
    }
}

__global__ __launch_bounds__(NT, 1) void kwinners_kernel(
    const float* __restrict__ x, const float* __restrict__ bf,
    float* __restrict__ out) {
    __shared__ uint32_t red[(NT / 64) * NPROBE];  // per-wave partial counts
    __shared__ int cglob[NPROBE];
    __shared__ uint32_t s_key[SCAP];
    __shared__ uint32_t s_idx[SCAP];
    __shared__ uint32_t bmap[N_UNITS / 32];  // 2 KB winner bitmap
    __shared__ int sc[1];

    const int tid = threadIdx.x;
    const int lane = tid & 63;
    const int w = tid >> 6;
    const int row = blockIdx.x;
    const float4* xrow = (const float4*)(x + (size_t)row * N_UNITS);
    const float4* bfv = (const float4*)bf;
    float* orow = out + (size_t)row * N_UNITS;

    bmap[tid] = 0u;           // NT == N_UNITS/32 exactly
    if (tid == 0) sc[0] = 0;  // ordered before first use by reduce barriers

    // Probes tuned for N(0,1)*boost, as full-key thresholds:
    // count(khi > P) == count(key > (fkey(pv) | 0xFFFF)). Constant-folded.
    uint32_t PF[NPROBE];
    {
        const float pv[NPROBE] = {1.90f, 1.70f, 1.55f, 1.43f, 1.33f, 1.25f,
                                  1.18f, 1.12f, 1.06f, 0.99f, 0.90f};
#pragma unroll
        for (int p = 0; p < NPROBE; ++p) PF[p] = fkey(pv[p]) | 0xFFFFu;
    }

    int cnt[NPROBE];
#pragma unroll
    for (int p = 0; p < NPROBE; ++p) cnt[p] = 0;

    uint4 kk[ITERS];  // full keys for this thread's 32 elements (32 VGPRs)

    // ---- fused: global load -> full keys in regs + per-lane counting ----
    // (pure loads + VALU: no LDS ops, atomics, or convergent ops, so the 16
    //  dwordx4 loads pipeline ahead of the compare chains)
#pragma unroll
    for (int j = 0; j < ITERS; ++j) {
        int i4 = tid + j * NT;
        float4 xv = xrow[i4];
        float4 bv = bfv[i4];
        kk[j].x = fkey(xv.x * bv.x);
        kk[j].y = fkey(xv.y * bv.y);
        kk[j].z = fkey(xv.z * bv.z);
        kk[j].w = fkey(xv.w * bv.w);
#pragma unroll
        for (int p = 0; p < NPROBE; ++p)
            cnt[p] += (kk[j].x > PF[p]) + (kk[j].y > PF[p]) +
                      (kk[j].z > PF[p]) + (kk[j].w > PF[p]);
    }

    // ---- block reduction of per-lane counters -> cglob ----
    auto reduce_counts = [&]() {
#pragma unroll
        for (int p = 0; p < NPROBE; ++p) {
            int v = cnt[p];
#pragma unroll
            for (int m2 = 32; m2 >= 1; m2 >>= 1) v += __shfl_xor(v, m2, 64);
            if (lane == 0) red[w * NPROBE + p] = (uint32_t)v;
        }
        __syncthreads();
        if (tid < NPROBE) {
            int s = 0;
#pragma unroll
            for (int ww = 0; ww < NT / 64; ++ww) s += (int)red[ww * NPROBE + tid];
            cglob[tid] = s;
        }
        __syncthreads();
    };
    reduce_counts();

    // ---- bracket (lo, hi] in full-key space: count(>hi) < K <= count(>lo) ----
    long lo, hi;   // thresholds in [-1, 2^32-1]
    int cab, cgl;  // cab = count(>hi), cgl = count(>lo)
    {
        int j = 0;
        while (j < NPROBE && cglob[j] < K_WIN) ++j;
        if (j == 0) {
            lo = (long)PF[0]; cgl = cglob[0]; hi = 0xFFFFFFFFL; cab = 0;
        } else if (j == NPROBE) {
            lo = -1; cgl = N_UNITS; hi = (long)PF[NPROBE - 1];
            cab = cglob[NPROBE - 1];
        } else {
            lo = (long)PF[j]; cgl = cglob[j]; hi = (long)PF[j - 1];
            cab = cglob[j - 1];
        }
    }
    int inB = cgl - cab;

    // ---- full-key refinement from registers until <= SCAP in bracket ----
    // Range shrinks >= 12x per round -> terminates (range<=1 => pure ties).
    // Block-uniform condition: barriers inside are safe.
    while (inB > SCAP && (hi - lo) > 1) {
        unsigned long range = (unsigned long)(hi - lo);
        // p-outer so only one 64-bit threshold is live at a time (VGPR).
#pragma unroll
        for (int p = 0; p < NPROBE; ++p) {
            long Tp = lo + (long)(range * (unsigned long)(NPROBE - p) /
                                  (NPROBE + 1));
            int c = 0;
#pragma unroll
            for (int j = 0; j < ITERS; ++j)
                c += ((long)kk[j].x > Tp) + ((long)kk[j].y > Tp) +
                     ((long)kk[j].z > Tp) + ((long)kk[j].w > Tp);
            cnt[p] = c;
        }
        reduce_counts();
        int j = 0;
        while (j < NPROBE && cglob[j] < K_WIN) ++j;
        const long llo = lo;  // recompute thresholds from OLD bracket
        auto Tof = [&](int p) {
            return llo + (long)(range * (unsigned long)(NPROBE - p) /
                                (NPROBE + 1));
        };
        if (j == 0) {
            lo = Tof(0); cgl = cglob[0];  // hi, cab unchanged
        } else if (j == NPROBE) {
            hi = Tof(NPROBE - 1); cab = cglob[NPROBE - 1];  // lo unchanged
        } else {
            lo = Tof(j); cgl = cglob[j]; hi = Tof(j - 1); cab = cglob[j - 1];
        }
        inB = cgl - cab;
    }
    const int need = K_WIN - cab;  // >= 1 by bracket invariant

    if (inB <= SCAP) {
        // ---- compact in-bracket (key, idx) into LDS ----
#pragma unroll
        for (int j = 0; j < ITERS; ++j) {
            int base = (tid + j * NT) * 4;
            uint32_t kv[4] = {kk[j].x, kk[j].y, kk[j].z, kk[j].w};
#pragma unroll
            for (int e = 0; e < 4; ++e) {
                long k = (long)kv[e];
                if (k > lo && k <= hi) {
                    int p = atomicAdd(&sc[0], 1);
                    if (p < SCAP) {
                        s_key[p] = kv[e];
                        s_idx[p] = (uint32_t)(base + e);
                    }
                }
            }
        }
        __syncthreads();
        const int sS = sc[0];  // == inB (exact same comparisons as counts)

        // ---- exact rank among <=256; (key desc, idx asc) = jax top_k ----
        for (int jj = tid; jj < sS; jj += NT) {
            uint32_t myk = s_key[jj];
            uint32_t myi = s_idx[jj];
            int r = 0;
            for (int l = 0; l < sS; ++l) {
                uint32_t lk = s_key[l];
                r += (lk > myk) || (lk == myk && s_idx[l] < myi);
            }
            if (r < need) atomicOr(&bmap[myi >> 5], 1u << (myi & 31));
        }
    } else {
        // Pathological: range collapsed (hi-lo==1) with >SCAP exact-key ties
        // at the boundary. Winners among key==hi are the first `need` by
        // index. Serial, unreachable on benchmark data; exact for any input.
        if (tid == 0) {
            const float* xr = x + (size_t)row * N_UNITS;
            int r = 0;
            for (int i = 0; i < N_UNITS && r < need; ++i) {
                uint32_t kf = fkey(xr[i] * bf[i]);
                if ((long)kf == hi) {
                    bmap[i >> 5] |= (1u << (i & 31));
                    ++r;
                }
            }
        }
    }
    __syncthreads();

    // ---- single coalesced output pass: (key > hi) | bitmap ----
#pragma unroll
    for (int j = 0; j < ITERS; ++j) {
        int f = tid + j * NT;
        uint32_t bm = bmap[f >> 3];  // word holds bits for 8 float4 groups
        int sh = (f & 7) * 4;
        float4 o;
        o.x = (((long)kk[j].x > hi) || ((bm >> (sh + 0)) & 1u)) ? 1.0f : 0.0f;
        o.y = (((long)kk[j].y > hi) || ((bm >> (sh + 1)) & 1u)) ? 1.0f : 0.0f;
        o.z = (((long)kk[j].z > hi) || ((bm >> (sh + 2)) & 1u)) ? 1.0f : 0.0f;
        o.w = (((long)kk[j].w > hi) || ((bm >> (sh + 3)) & 1u)) ? 1.0f : 0.0f;
        ((float4*)orow)[f] = o;
    }
}

extern "C" void kernel_launch(void* const* d_in, const int* in_sizes, int n_in,
                              void* d_out, int out_size, void* d_ws,
                              size_t ws_size, hipStream_t stream) {
    const float* x = (const float*)d_in[0];
    const float* duty = (const float*)d_in[1];
    float* out = (float*)d_out;
    float* bf = (float*)d_ws;  // 16384 floats = 64 KB scratch

    hipLaunchKernelGGL(boost_kernel, dim3(N_UNITS / 256), dim3(256), 0, stream,
                       duty, bf, N_UNITS);
    int rows = out_size / N_UNITS;  // 4096
    hipLaunchKernelGGL(kwinners_kernel, dim3(rows), dim3(NT), 0, stream, x, bf,
                       out);
}

// Round 5
// 439.007 us; speedup vs baseline: 1.9537x; 1.1764x over previous
//
#include <hip/hip_runtime.h>
#include <math.h>
#include <stdint.h>

// KWinners: per-row top-K binary mask with duty-cycle boosting.
// x: (4096, 16384) fp32, duty: (16384,) fp32, out: (4096, 16384) fp32 0/1 mask.
//
// Round-7 design (deep load pipeline):
//  - LOAD-ALL-THEN-COMPUTE: all 16 dwordx4 loads (8x x, 8x bf) issued before
//    any key math. Round-6 interleaved load->count in source, so the compiler
//    rolled a shallow 2-deep pipeline (VGPR_Count=48) and the kernel was
//    latency-bound (all pipes <45%). 16 KB/wave in flight >> ~9 KB/CU needed
//    to saturate HBM.
//  - 7 probes (was 11): row thresholds concentrate at ~1.20 +/- 0.01
//    (order-stat std ~0.008), center gaps 0.04 keep bracket pop ~200-260.
//    Saves ~8 VALU ops/element in the hot loop. SCAP=320 keeps refinement
//    rare; full-key refinement from registers covers any outlier row.
//  - Rank keys packed as u64 (key<<32)|~idx: (key desc, idx asc) == u64 desc,
//    one ds_read_b64 + one 64-bit compare per rank iteration.
//  - u32 threshold compares in hot passes (hi in [0,2^32-1] maps exactly).
//  - Winners marked in 2 KB LDS bitmap; single coalesced float4 output pass:
//    (key > hi) | bitmap. No scattered global writes.
//  - Exact for ANY input: register refinement loop + serial tie fallback.

#define N_UNITS 16384
#define K_WIN 655
#define NT 512
#define NPROBE 7
#define SCAP 320
#define ITERS (N_UNITS / (NT * 4))  // 8

// Order-preserving float -> uint map: larger float => larger key.
__device__ __forceinline__ uint32_t fkey(float f) {
    uint32_t b = __float_as_uint(f);
    uint32_t m = (uint32_t)((int32_t)b >> 31) | 0x80000000u;
    return b ^ m;
}

__global__ void boost_kernel(const float* __restrict__ duty,
                             float* __restrict__ bf, int n) {
    int i = blockIdx.x * blockDim.x + threadIdx.x;
    if (i < n) {
        const float td = 0.03997802734375f;  // 655/16384, exact in fp32
        float s = td - duty[i];              // fp32 subtract, matches ref
        bf[i] = (float)exp((double)s);       // correctly-rounded fp32 exp
    }
}

__global__ __launch_bounds__(NT, 1) void kwinners_kernel(
    const float* __restrict__ x, const float* __restrict__ bf,
    float* __restrict__ out) {
    __shared__ uint32_t red[(NT / 64) * NPROBE];  // per-wave partial counts
    __shared__ int cglob[NPROBE];
    __shared__ unsigned long long s_pk[SCAP];  // (key<<32)|~idx, 2.5 KB
    __shared__ uint32_t bmap[N_UNITS / 32];    // 2 KB winner bitmap
    __shared__ int sc[1];

    const int tid = threadIdx.x;
    const int lane = tid & 63;
    const int w = tid >> 6;
    const int row = blockIdx.x;
    const float4* xrow = (const float4*)(x + (size_t)row * N_UNITS);
    const float4* bfv = (const float4*)bf;
    float* orow = out + (size_t)row * N_UNITS;

    bmap[tid] = 0u;           // NT == N_UNITS/32 exactly
    if (tid == 0) sc[0] = 0;  // ordered before first use by reduce barriers

    // Probes as full-key thresholds (constant-folded):
    // count(key > (fkey(pv)|0xFFFF)) brackets the row threshold.
    uint32_t PF[NPROBE];
    {
        const float pv[NPROBE] = {1.45f, 1.32f, 1.24f, 1.20f,
                                  1.16f, 1.10f, 1.00f};
#pragma unroll
        for (int p = 0; p < NPROBE; ++p) PF[p] = fkey(pv[p]) | 0xFFFFu;
    }

    // ---- phase 1: issue ALL global loads (deep pipeline) ----
    float4 xv[ITERS];
    float4 bv[ITERS];
#pragma unroll
    for (int j = 0; j < ITERS; ++j) xv[j] = xrow[tid + j * NT];
#pragma unroll
    for (int j = 0; j < ITERS; ++j) bv[j] = bfv[tid + j * NT];

    // ---- phase 2: keys + probe counting (pure register VALU) ----
    int cnt[NPROBE];
#pragma unroll
    for (int p = 0; p < NPROBE; ++p) cnt[p] = 0;

    uint4 kk[ITERS];  // full keys for this thread's 32 elements
#pragma unroll
    for (int j = 0; j < ITERS; ++j) {
        kk[j].x = fkey(xv[j].x * bv[j].x);
        kk[j].y = fkey(xv[j].y * bv[j].y);
        kk[j].z = fkey(xv[j].z * bv[j].z);
        kk[j].w = fkey(xv[j].w * bv[j].w);
#pragma unroll
        for (int p = 0; p < NPROBE; ++p)
            cnt[p] += (kk[j].x > PF[p]) + (kk[j].y > PF[p]) +
                      (kk[j].z > PF[p]) + (kk[j].w > PF[p]);
    }

    // ---- block reduction of per-lane counters -> cglob ----
    auto reduce_counts = [&]() {
#pragma unroll
        for (int p = 0; p < NPROBE; ++p) {
            int v = cnt[p];
#pragma unroll
            for (int m2 = 32; m2 >= 1; m2 >>= 1) v += __shfl_xor(v, m2, 64);
            if (lane == 0) red[w * NPROBE + p] = (uint32_t)v;
        }
        __syncthreads();
        if (tid < NPROBE) {
            int s = 0;
#pragma unroll
            for (int ww = 0; ww < NT / 64; ++ww) s += (int)red[ww * NPROBE + tid];
            cglob[tid] = s;
        }
        __syncthreads();
    };
    reduce_counts();

    // ---- bracket (lo, hi] in full-key space: count(>hi) < K <= count(>lo) ----
    long lo, hi;   // thresholds in [-1, 2^32-1]
    int cab, cgl;  // cab = count(>hi), cgl = count(>lo)
    {
        int j = 0;
        while (j < NPROBE && cglob[j] < K_WIN) ++j;
        if (j == 0) {
            lo = (long)PF[0]; cgl = cglob[0]; hi = 0xFFFFFFFFL; cab = 0;
        } else if (j == NPROBE) {
            lo = -1; cgl = N_UNITS; hi = (long)PF[NPROBE - 1];
            cab = cglob[NPROBE - 1];
        } else {
            lo = (long)PF[j]; cgl = cglob[j]; hi = (long)PF[j - 1];
            cab = cglob[j - 1];
        }
    }
    int inB = cgl - cab;

    // ---- full-key refinement from registers until <= SCAP in bracket ----
    // Range shrinks >= 8x per round -> terminates (range<=1 => pure ties).
    // Block-uniform condition: barriers inside are safe.
    while (inB > SCAP && (hi - lo) > 1) {
        unsigned long range = (unsigned long)(hi - lo);
#pragma unroll
        for (int p = 0; p < NPROBE; ++p) {
            long Tp = lo + (long)(range * (unsigned long)(NPROBE - p) /
                                  (NPROBE + 1));
            int c = 0;
#pragma unroll
            for (int j = 0; j < ITERS; ++j)
                c += ((long)kk[j].x > Tp) + ((long)kk[j].y > Tp) +
                     ((long)kk[j].z > Tp) + ((long)kk[j].w > Tp);
            cnt[p] = c;
        }
        reduce_counts();
        int j = 0;
        while (j < NPROBE && cglob[j] < K_WIN) ++j;
        const long llo = lo;  // recompute thresholds from OLD bracket
        auto Tof = [&](int p) {
            return llo + (long)(range * (unsigned long)(NPROBE - p) /
                                (NPROBE + 1));
        };
        if (j == 0) {
            lo = Tof(0); cgl = cglob[0];  // hi, cab unchanged
        } else if (j == NPROBE) {
            hi = Tof(NPROBE - 1); cab = cglob[NPROBE - 1];  // lo unchanged
        } else {
            lo = Tof(j); cgl = cglob[j]; hi = Tof(j - 1); cab = cglob[j - 1];
        }
        inB = cgl - cab;
    }
    const int need = K_WIN - cab;  // >= 1 by bracket invariant

    const uint32_t hi32 = (uint32_t)hi;  // hi==2^32-1 -> "key>hi32" all-false
    const uint32_t lo32 = (uint32_t)lo;
    const bool lneg = (lo < 0);

    if (inB <= SCAP) {
        // ---- compact in-bracket packed (key, ~idx) into LDS ----
#pragma unroll
        for (int j = 0; j < ITERS; ++j) {
            int base = (tid + j * NT) * 4;
            uint32_t kv[4] = {kk[j].x, kk[j].y, kk[j].z, kk[j].w};
#pragma unroll
            for (int e = 0; e < 4; ++e) {
                bool in = ((kv[e] > lo32) || lneg) && (kv[e] <= hi32);
                if (in) {
                    int p = atomicAdd(&sc[0], 1);
                    if (p < SCAP)
                        s_pk[p] = ((unsigned long long)kv[e] << 32) |
                                  (uint32_t)(~(uint32_t)(base + e));
                }
            }
        }
        __syncthreads();
        const int sS = sc[0];  // == inB (same comparisons as the counts)

        // ---- exact rank among <=SCAP; u64 desc == (key desc, idx asc) ----
        for (int jj = tid; jj < sS; jj += NT) {
            unsigned long long my = s_pk[jj];
            int r = 0;
            for (int l = 0; l < sS; ++l) r += (s_pk[l] > my);
            if (r < need) {
                uint32_t myi = ~(uint32_t)my;
                atomicOr(&bmap[myi >> 5], 1u << (myi & 31));
            }
        }
    } else {
        // Pathological: range collapsed (hi-lo==1) with >SCAP exact-key ties
        // at the boundary. Winners among key==hi are the first `need` by
        // index. Serial, unreachable on benchmark data; exact for any input.
        if (tid == 0) {
            const float* xr = x + (size_t)row * N_UNITS;
            int r = 0;
            for (int i = 0; i < N_UNITS && r < need; ++i) {
                uint32_t kf = fkey(xr[i] * bf[i]);
                if ((long)kf == hi) {
                    bmap[i >> 5] |= (1u << (i & 31));
                    ++r;
                }
            }
        }
    }
    __syncthreads();

    // ---- single coalesced output pass: (key > hi) | bitmap ----
#pragma unroll
    for (int j = 0; j < ITERS; ++j) {
        int f = tid + j * NT;
        uint32_t bm = bmap[f >> 3];  // word holds bits for 8 float4 groups
        int sh = (f & 7) * 4;
        float4 o;
        o.x = ((kk[j].x > hi32) || ((bm >> (sh + 0)) & 1u)) ? 1.0f : 0.0f;
        o.y = ((kk[j].y > hi32) || ((bm >> (sh + 1)) & 1u)) ? 1.0f : 0.0f;
        o.z = ((kk[j].z > hi32) || ((bm >> (sh + 2)) & 1u)) ? 1.0f : 0.0f;
        o.w = ((kk[j].w > hi32) || ((bm >> (sh + 3)) & 1u)) ? 1.0f : 0.0f;
        ((float4*)orow)[f] = o;
    }
}

extern "C" void kernel_launch(void* const* d_in, const int* in_sizes, int n_in,
                              void* d_out, int out_size, void* d_ws,
                              size_t ws_size, hipStream_t stream) {
    const float* x = (const float*)d_in[0];
    const float* duty = (const float*)d_in[1];
    float* out = (float*)d_out;
    float* bf = (float*)d_ws;  // 16384 floats = 64 KB scratch

    hipLaunchKernelGGL(boost_kernel, dim3(N_UNITS / 256), dim3(256), 0, stream,
                       duty, bf, N_UNITS);
    int rows = out_size / N_UNITS;  // 4096
    hipLaunchKernelGGL(kwinners_kernel, dim3(rows), dim3(NT), 0, stream, x, bf,
                       out);
}